// Round 20
// baseline (112.260 us; speedup 1.0000x reference)
//
#include <hip/hip_runtime.h>

#define N_NODES 100000
#define N_EDGES 1600000
#define FT 128

#define NBUCK 391   // partition buckets: 256 rows each (row >> 8)
#define EPB 4096    // edges per partition block
#define NBLKP ((N_EDGES + EPB - 1) / EPB)  // 391 partition blocks
#define CAP 1536    // LDS-staged edges per 64-row quarter (avg 1023, +16 sigma)
#define CAPB 4800   // region capacity per bucket (avg 4092, +11 sigma)
#define OVFCAP 65536
#define GEMM_BLOCKS ((N_NODES + 255) / 256)  // 391
#define SPMM_GRID (8 * 4 * ((NBUCK + 7) / 8))  // 1568 (4 dead blocks)

// ---- workspace layout (bytes) — identical to R19 ---------------------------
#define OFF_H 0
#define OFF_BUCKETED 25600000
#define OFF_GCUR 40614400
#define OFF_NOVF 40615964
#define OFF_OVFREC 40615968
#define OFF_OVFBUCK 41140256
#define WS_NEEDED 41402400

typedef __attribute__((ext_vector_type(8))) short bf16x8;
typedef __attribute__((ext_vector_type(4))) float f32x4;

static __device__ __forceinline__ ushort f2bf(float f) {
  const unsigned u = __float_as_uint(f);
  return (ushort)((u + 0x7FFF + ((u >> 16) & 1)) >> 16);
}
static __device__ __forceinline__ float bf2f(ushort s) {
  return __uint_as_float((unsigned)s << 16);
}

// Shared-memory overlay: gemm half uses whi; partC half uses pc.
union SharedU {
  ushort whi[16384];  // 32 KB
  struct {
    int2 stage[EPB];  // 32 KB sorted-by-bucket records
    int loc[NBUCK + 1];  // exclusive local offsets (+ total)
    int cur[NBUCK];      // pass-1 hist, then pass-2 cursors
    int gbase[NBUCK];    // per-bucket reserved global base
  } pc;                  // 36.6 KB
};

// ---------------------------------------------------------------------------
// FUSED gemm + partC3: gemm half unchanged; partC half now LDS counting-sorts
// the block's edges BY BUCKET and writes each bucket's run contiguously
// (burst-coalesced) into the bucket's reserved region slice.
// ---------------------------------------------------------------------------
__global__ __launch_bounds__(256) void fused_gemm_partC_kernel(
    const float* __restrict__ x,
    const float* __restrict__ W,
    const float* __restrict__ b,
    ushort* __restrict__ h,
    const int* __restrict__ erows,
    const int* __restrict__ ecols,
    const float* __restrict__ evals,
    int* gcur,
    int* novf,
    int2* __restrict__ ovf_rec,
    int* __restrict__ ovf_buck,
    int2* __restrict__ bucketed) {
  __shared__ SharedU shm;
  const int tid = threadIdx.x;

  if (blockIdx.x < GEMM_BLOCKS) {
    // ------------------------- gemm half ---------------------------------
    for (int idx = tid; idx < 16384; idx += 256) {
      const int k = idx >> 7;
      const int col = idx & 127;
      const ushort hi = f2bf(W[idx]);
      const int lane_ = (((k >> 3) & 3) << 4) | (col & 15);
      const int pos =
          ((((k >> 5) << 3) + (col >> 4)) * 64 + lane_) * 8 + (k & 7);
      shm.whi[pos] = hi;
    }
    __syncthreads();

    const int w = tid >> 6;
    const int lane = tid & 63;
    const int r0 = blockIdx.x * 256 + w * 64;
    const int arow = lane & 15;
    const int kgrp = (lane >> 4) << 3;

    float bias_v[8];
#pragma unroll
    for (int ct = 0; ct < 8; ++ct) bias_v[ct] = b[ct * 16 + (lane & 15)];

    f32x4 acc[4][8];
#pragma unroll
    for (int rf = 0; rf < 4; ++rf)
#pragma unroll
      for (int ct = 0; ct < 8; ++ct) acc[rf][ct] = (f32x4){0.f, 0.f, 0.f, 0.f};

#pragma unroll
    for (int ks = 0; ks < 4; ++ks) {
      bf16x8 afr[4];
#pragma unroll
      for (int rf = 0; rf < 4; ++rf) {
        int r = r0 + rf * 16 + arow;
        r = (r < N_NODES) ? r : (N_NODES - 1);
        const float* xp = x + (size_t)r * FT + ks * 32 + kgrp;
        const float4 u0 = *(const float4*)xp;
        const float4 u1 = *(const float4*)(xp + 4);
        bf16x8 a;
        a[0] = (short)f2bf(u0.x);
        a[1] = (short)f2bf(u0.y);
        a[2] = (short)f2bf(u0.z);
        a[3] = (short)f2bf(u0.w);
        a[4] = (short)f2bf(u1.x);
        a[5] = (short)f2bf(u1.y);
        a[6] = (short)f2bf(u1.z);
        a[7] = (short)f2bf(u1.w);
        afr[rf] = a;
      }
#pragma unroll
      for (int ct = 0; ct < 8; ++ct) {
        const int fo = ((ks * 8 + ct) * 64 + lane) * 8;
        const bf16x8 bh = *(const bf16x8*)&shm.whi[fo];
#pragma unroll
        for (int rf = 0; rf < 4; ++rf) {
          acc[rf][ct] = __builtin_amdgcn_mfma_f32_16x16x32_bf16(
              afr[rf], bh, acc[rf][ct], 0, 0, 0);
        }
      }
    }

    const int crow0 = (lane >> 4) << 2;
    const int ccol = lane & 15;
#pragma unroll
    for (int rf = 0; rf < 4; ++rf) {
#pragma unroll
      for (int ct = 0; ct < 8; ++ct) {
        const int col = ct * 16 + ccol;
#pragma unroll
        for (int i = 0; i < 4; ++i) {
          const int row = r0 + rf * 16 + crow0 + i;
          if (row < N_NODES)
            h[(size_t)row * FT + col] = f2bf(acc[rf][ct][i] + bias_v[ct]);
        }
      }
    }
  } else {
    // ------------------------- partC3 half -------------------------------
    const int bid = blockIdx.x - GEMM_BLOCKS;
    for (int j = tid; j < NBUCK; j += 256) shm.pc.cur[j] = 0;
    __syncthreads();

    const int base4 = bid * (EPB / 4);
    int4 rreg[EPB / 4 / 256];  // register-staged rows (4 x int4)
    // pass 1: histogram (rows staged in registers)
#pragma unroll
    for (int it = 0; it < EPB / 4 / 256; ++it) {
      const int idx4 = base4 + it * 256 + tid;
      int4 r = {N_NODES, N_NODES, N_NODES, N_NODES};  // sentinel (skipped)
      if (idx4 < N_EDGES / 4) {
        r = ((const int4*)erows)[idx4];
        atomicAdd(&shm.pc.cur[r.x >> 8], 1);
        atomicAdd(&shm.pc.cur[r.y >> 8], 1);
        atomicAdd(&shm.pc.cur[r.z >> 8], 1);
        atomicAdd(&shm.pc.cur[r.w >> 8], 1);
      }
      rreg[it] = r;
    }
    __syncthreads();

    // bulk global reservation (one with-return atomic per non-empty bucket)
    for (int j = tid; j < NBUCK; j += 256) {
      const int hj = shm.pc.cur[j];
      shm.pc.gbase[j] = (hj > 0) ? atomicAdd(&gcur[j], hj) : 0;
    }

    // exclusive scan cur -> loc. Thread t owns buckets [2t, 2t+2).
    {
      __shared__ int ps[256];
      const int b0 = tid * 2;
      int c0 = (b0 < NBUCK) ? shm.pc.cur[b0] : 0;
      int c1 = (b0 + 1 < NBUCK) ? shm.pc.cur[b0 + 1] : 0;
      ps[tid] = c0 + c1;
      __syncthreads();
#pragma unroll
      for (int d = 1; d < 256; d <<= 1) {
        const int u = (tid >= d) ? ps[tid - d] : 0;
        __syncthreads();
        ps[tid] += u;
        __syncthreads();
      }
      int run = (tid == 0) ? 0 : ps[tid - 1];
      if (b0 < NBUCK) shm.pc.loc[b0] = run;
      run += c0;
      if (b0 + 1 < NBUCK) shm.pc.loc[b0 + 1] = run;
      if (tid == 255) shm.pc.loc[NBUCK] = ps[255];
    }
    __syncthreads();
    for (int j = tid; j < NBUCK; j += 256) shm.pc.cur[j] = shm.pc.loc[j];
    __syncthreads();

    // pass 2: counting-sort records into stage (by bucket)
#pragma unroll
    for (int it = 0; it < EPB / 4 / 256; ++it) {
      const int idx4 = base4 + it * 256 + tid;
      if (idx4 < N_EDGES / 4) {
        const int4 r = rreg[it];
        const int4 c = ((const int4*)ecols)[idx4];
        const float4 v = ((const float4*)evals)[idx4];
        int bb, p;
        int2 rec;
#define STG(RR, CC, VV)                                  \
        bb = (RR) >> 8;                                  \
        rec.x = (((RR) & 255) << 24) | (CC);             \
        rec.y = __float_as_int(VV);                      \
        p = atomicAdd(&shm.pc.cur[bb], 1);               \
        shm.pc.stage[p] = rec;
        STG(r.x, c.x, v.x)
        STG(r.y, c.y, v.y)
        STG(r.z, c.z, v.z)
        STG(r.w, c.w, v.w)
#undef STG
      }
    }
    __syncthreads();

    // write phase: consecutive threads write consecutive slots -> bucket runs
    const int total = shm.pc.loc[NBUCK];
    for (int i = tid; i < total; i += 256) {
      // binary search: largest bb with loc[bb] <= i
      int lo = 0, hi = NBUCK - 1;
#pragma unroll
      for (int s = 0; s < 9; ++s) {
        const int mid = (lo + hi + 1) >> 1;
        if (shm.pc.loc[mid] <= i) lo = mid; else hi = mid - 1;
      }
      const int bb = lo;
      const int gp = shm.pc.gbase[bb] + (i - shm.pc.loc[bb]);
      const int2 rec = shm.pc.stage[i];
      if (gp < CAPB) {
        bucketed[(size_t)bb * CAPB + gp] = rec;
      } else {
        const int op = atomicAdd(novf, 1);
        if (op < OVFCAP) { ovf_rec[op] = rec; ovf_buck[op] = bb; }
      }
    }
  }
}

// ---------------------------------------------------------------------------
// Fused filter + sort + SpMM (byte-identical to R19).
// ---------------------------------------------------------------------------
__global__ __launch_bounds__(512) void spmm_bucket_kernel(
    const int2* __restrict__ bucketed,
    const int* __restrict__ gcur,
    const int* __restrict__ novf,
    const int2* __restrict__ ovf_rec,
    const int* __restrict__ ovf_buck,
    const ushort* __restrict__ h,
    float* __restrict__ out) {
  __shared__ int2 tmp[CAP];
  __shared__ int2 eds[CAP];
  __shared__ int cnt[64];
  __shared__ int pos[64];
  __shared__ int cur[64];
  __shared__ int ns;
  const int p_ = blockIdx.x;
  const int x_ = p_ & 7;
  const int m_ = p_ >> 3;
  const int q = m_ & 3;
  const int b = 8 * (m_ >> 2) + x_;
  if (b >= NBUCK) return;
  const int t = threadIdx.x;
  const int beg = b * CAPB;
  const int fill = gcur[b];
  const int end = beg + ((fill < CAPB) ? fill : CAPB);
  const int nov = *novf;

  if (t < 64) cnt[t] = 0;
  if (t == 0) ns = 0;
  __syncthreads();

  for (int i = beg + t; i < end; i += 512) {
    const int2 rec = bucketed[i];
    const int r8 = ((unsigned)rec.x) >> 24;
    if ((r8 >> 6) == q) {
      const int p = atomicAdd(&ns, 1);
      if (p < CAP) {
        tmp[p] = rec;
        atomicAdd(&cnt[r8 & 63], 1);
      }
    }
  }
  __syncthreads();

  const int m = (ns < CAP) ? ns : CAP;
  const bool overflow = (ns > CAP);

  if (t < 64) pos[t] = cnt[t];
  __syncthreads();
#pragma unroll
  for (int d = 1; d < 64; d <<= 1) {
    int u = 0;
    if (t < 64 && t >= d) u = pos[t - d];
    __syncthreads();
    if (t < 64) pos[t] += u;
    __syncthreads();
  }
  if (t < 64) {
    const int excl = pos[t] - cnt[t];
    pos[t] = excl;
    cur[t] = excl;
  }
  __syncthreads();

  for (int i = t; i < m; i += 512) {
    const int2 rec = tmp[i];
    const int r6 = (((unsigned)rec.x) >> 24) & 63;
    const int p = atomicAdd(&cur[r6], 1);
    eds[p] = (int2){rec.x & 0x00FFFFFF, rec.y};
  }
  __syncthreads();

  const int g = t >> 5;
  const int lane = t & 31;
  const int j = lane * 4;

  for (int rr = 0; rr < 4; ++rr) {
    const int r = rr * 16 + g;
    const int row = b * 256 + q * 64 + r;
    const int rbeg = pos[r];
    const int rend = cur[r];

    float a0 = 0.f, a1 = 0.f, a2 = 0.f, a3 = 0.f;
    int e = rbeg;
    for (; e + 3 < rend; e += 4) {
      const int2 p0 = eds[e];
      const int2 p1 = eds[e + 1];
      const int2 p2 = eds[e + 2];
      const int2 p3 = eds[e + 3];
      const ushort4 q0 = *(const ushort4*)(h + (size_t)p0.x * FT + j);
      const ushort4 q1 = *(const ushort4*)(h + (size_t)p1.x * FT + j);
      const ushort4 q2 = *(const ushort4*)(h + (size_t)p2.x * FT + j);
      const ushort4 q3 = *(const ushort4*)(h + (size_t)p3.x * FT + j);
      const float v0 = __int_as_float(p0.y);
      const float v1 = __int_as_float(p1.y);
      const float v2 = __int_as_float(p2.y);
      const float v3 = __int_as_float(p3.y);
      a0 = fmaf(v0, bf2f(q0.x), a0);
      a1 = fmaf(v0, bf2f(q0.y), a1);
      a2 = fmaf(v0, bf2f(q0.z), a2);
      a3 = fmaf(v0, bf2f(q0.w), a3);
      a0 = fmaf(v1, bf2f(q1.x), a0);
      a1 = fmaf(v1, bf2f(q1.y), a1);
      a2 = fmaf(v1, bf2f(q1.z), a2);
      a3 = fmaf(v1, bf2f(q1.w), a3);
      a0 = fmaf(v2, bf2f(q2.x), a0);
      a1 = fmaf(v2, bf2f(q2.y), a1);
      a2 = fmaf(v2, bf2f(q2.z), a2);
      a3 = fmaf(v2, bf2f(q2.w), a3);
      a0 = fmaf(v3, bf2f(q3.x), a0);
      a1 = fmaf(v3, bf2f(q3.y), a1);
      a2 = fmaf(v3, bf2f(q3.z), a2);
      a3 = fmaf(v3, bf2f(q3.w), a3);
    }
    for (; e < rend; ++e) {
      const int2 p0 = eds[e];
      const float v0 = __int_as_float(p0.y);
      const ushort4 q0 = *(const ushort4*)(h + (size_t)p0.x * FT + j);
      a0 = fmaf(v0, bf2f(q0.x), a0);
      a1 = fmaf(v0, bf2f(q0.y), a1);
      a2 = fmaf(v0, bf2f(q0.z), a2);
      a3 = fmaf(v0, bf2f(q0.w), a3);
    }
    if (overflow) {
      int seen = 0;
      const int have = rend - rbeg;
      for (int i = beg; i < end; ++i) {
        const int2 rec = bucketed[i];
        const int r8 = ((unsigned)rec.x) >> 24;
        if ((r8 >> 6) == q && (r8 & 63) == r) {
          ++seen;
          if (seen > have) {
            const float v0 = __int_as_float(rec.y);
            const ushort4 q0 =
                *(const ushort4*)(h + (size_t)(rec.x & 0x00FFFFFF) * FT + j);
            a0 = fmaf(v0, bf2f(q0.x), a0);
            a1 = fmaf(v0, bf2f(q0.y), a1);
            a2 = fmaf(v0, bf2f(q0.z), a2);
            a3 = fmaf(v0, bf2f(q0.w), a3);
          }
        }
      }
    }
    if (nov > 0) {
      const int lim = (nov < OVFCAP) ? nov : OVFCAP;
      for (int i = 0; i < lim; ++i) {
        if (ovf_buck[i] == b) {
          const int2 rec = ovf_rec[i];
          const int r8 = ((unsigned)rec.x) >> 24;
          if ((r8 >> 6) == q && (r8 & 63) == r) {
            const float v0 = __int_as_float(rec.y);
            const ushort4 q0 =
                *(const ushort4*)(h + (size_t)(rec.x & 0x00FFFFFF) * FT + j);
            a0 = fmaf(v0, bf2f(q0.x), a0);
            a1 = fmaf(v0, bf2f(q0.y), a1);
            a2 = fmaf(v0, bf2f(q0.z), a2);
            a3 = fmaf(v0, bf2f(q0.w), a3);
          }
        }
      }
    }

    if (row < N_NODES) {
      float4 o;
      o.x = fmaxf(a0, 0.f);
      o.y = fmaxf(a1, 0.f);
      o.z = fmaxf(a2, 0.f);
      o.w = fmaxf(a3, 0.f);
      *(float4*)(out + (size_t)row * FT + j) = o;
    }
  }
}

// ---------------------------------------------------------------------------
// Fallback (small ws): standalone bf16-h gemm + atomic scatter + relu.
// ---------------------------------------------------------------------------
__global__ __launch_bounds__(256) void gemm_bias_kernel(
    const float* __restrict__ x,
    const float* __restrict__ W,
    const float* __restrict__ b,
    ushort* __restrict__ h) {
  __shared__ __align__(16) ushort whi[16384];
  const int tid = threadIdx.x;

  for (int idx = tid; idx < 16384; idx += 256) {
    const int k = idx >> 7;
    const int col = idx & 127;
    const ushort hi = f2bf(W[idx]);
    const int lane_ = (((k >> 3) & 3) << 4) | (col & 15);
    const int pos = ((((k >> 5) << 3) + (col >> 4)) * 64 + lane_) * 8 + (k & 7);
    whi[pos] = hi;
  }
  __syncthreads();

  const int w = tid >> 6;
  const int lane = tid & 63;
  const int r0 = blockIdx.x * 256 + w * 64;
  const int arow = lane & 15;
  const int kgrp = (lane >> 4) << 3;

  float bias_v[8];
#pragma unroll
  for (int ct = 0; ct < 8; ++ct) bias_v[ct] = b[ct * 16 + (lane & 15)];

  f32x4 acc[4][8];
#pragma unroll
  for (int rf = 0; rf < 4; ++rf)
#pragma unroll
    for (int ct = 0; ct < 8; ++ct) acc[rf][ct] = (f32x4){0.f, 0.f, 0.f, 0.f};

#pragma unroll
  for (int ks = 0; ks < 4; ++ks) {
    bf16x8 afr[4];
#pragma unroll
    for (int rf = 0; rf < 4; ++rf) {
      int r = r0 + rf * 16 + arow;
      r = (r < N_NODES) ? r : (N_NODES - 1);
      const float* xp = x + (size_t)r * FT + ks * 32 + kgrp;
      const float4 u0 = *(const float4*)xp;
      const float4 u1 = *(const float4*)(xp + 4);
      bf16x8 a;
      a[0] = (short)f2bf(u0.x);
      a[1] = (short)f2bf(u0.y);
      a[2] = (short)f2bf(u0.z);
      a[3] = (short)f2bf(u0.w);
      a[4] = (short)f2bf(u1.x);
      a[5] = (short)f2bf(u1.y);
      a[6] = (short)f2bf(u1.z);
      a[7] = (short)f2bf(u1.w);
      afr[rf] = a;
    }
#pragma unroll
    for (int ct = 0; ct < 8; ++ct) {
      const int fo = ((ks * 8 + ct) * 64 + lane) * 8;
      const bf16x8 bh = *(const bf16x8*)&whi[fo];
#pragma unroll
      for (int rf = 0; rf < 4; ++rf) {
        acc[rf][ct] = __builtin_amdgcn_mfma_f32_16x16x32_bf16(
            afr[rf], bh, acc[rf][ct], 0, 0, 0);
      }
    }
  }

  const int crow0 = (lane >> 4) << 2;
  const int ccol = lane & 15;
#pragma unroll
  for (int rf = 0; rf < 4; ++rf) {
#pragma unroll
    for (int ct = 0; ct < 8; ++ct) {
      const int col = ct * 16 + ccol;
#pragma unroll
      for (int i = 0; i < 4; ++i) {
        const int row = r0 + rf * 16 + crow0 + i;
        if (row < N_NODES)
          h[(size_t)row * FT + col] = f2bf(acc[rf][ct][i] + bias_v[ct]);
      }
    }
  }
}

__global__ __launch_bounds__(256) void edge_scatter_kernel(
    const int* __restrict__ erows,
    const int* __restrict__ ecols,
    const float* __restrict__ evals,
    const ushort* __restrict__ h,
    float* out) {
  const int tid = threadIdx.x;
  const int e = blockIdx.x * 8 + (tid >> 5);
  if (e >= N_EDGES) return;
  const int r = erows[e];
  const int c = ecols[e];
  const float v = evals[e];
  const int j = (tid & 31) * 4;
  const ushort4 q = *(const ushort4*)(h + (size_t)c * FT + j);
  float* op = out + (size_t)r * FT + j;
  atomicAdd(op + 0, v * bf2f(q.x));
  atomicAdd(op + 1, v * bf2f(q.y));
  atomicAdd(op + 2, v * bf2f(q.z));
  atomicAdd(op + 3, v * bf2f(q.w));
}

__global__ __launch_bounds__(256) void relu_kernel(float* out, int n4) {
  const int i = blockIdx.x * blockDim.x + threadIdx.x;
  if (i < n4) {
    float4 v = ((float4*)out)[i];
    v.x = fmaxf(v.x, 0.f);
    v.y = fmaxf(v.y, 0.f);
    v.z = fmaxf(v.z, 0.f);
    v.w = fmaxf(v.w, 0.f);
    ((float4*)out)[i] = v;
  }
}

extern "C" void kernel_launch(void* const* d_in, const int* in_sizes, int n_in,
                              void* d_out, int out_size, void* d_ws, size_t ws_size,
                              hipStream_t stream) {
  const float* x = (const float*)d_in[0];
  const int* erows = (const int*)d_in[1];
  const int* ecols = (const int*)d_in[2];
  const float* evals = (const float*)d_in[3];
  const float* W = (const float*)d_in[4];
  const float* b = (const float*)d_in[5];
  float* out = (float*)d_out;

  char* ws = (char*)d_ws;
  ushort* h = (ushort*)(ws + OFF_H);

  if (ws_size >= (size_t)WS_NEEDED) {
    int2* bucketed = (int2*)(ws + OFF_BUCKETED);
    int* gcur = (int*)(ws + OFF_GCUR);
    int* novf = (int*)(ws + OFF_NOVF);
    int2* ovf_rec = (int2*)(ws + OFF_OVFREC);
    int* ovf_buck = (int*)(ws + OFF_OVFBUCK);

    hipMemsetAsync(gcur, 0, (NBUCK + 1) * sizeof(int), stream);
    fused_gemm_partC_kernel<<<GEMM_BLOCKS + NBLKP, 256, 0, stream>>>(
        x, W, b, h, erows, ecols, evals, gcur, novf, ovf_rec, ovf_buck,
        bucketed);
    spmm_bucket_kernel<<<SPMM_GRID, 512, 0, stream>>>(
        bucketed, gcur, novf, ovf_rec, ovf_buck, h, out);
  } else {
    gemm_bias_kernel<<<GEMM_BLOCKS, 256, 0, stream>>>(x, W, b, h);
    hipMemsetAsync(d_out, 0, (size_t)out_size * sizeof(float), stream);
    edge_scatter_kernel<<<(N_EDGES + 7) / 8, 256, 0, stream>>>(erows, ecols,
                                                               evals, h, out);
    const int n4 = out_size / 4;
    relu_kernel<<<(n4 + 255) / 256, 256, 0, stream>>>(out, n4);
  }
}

// Round 21
// 107.720 us; speedup vs baseline: 1.0421x; 1.0421x over previous
//
#include <hip/hip_runtime.h>

#define N_NODES 100000
#define N_EDGES 1600000
#define FT 128

#define NBUCK 391   // partition buckets: 256 rows each (row >> 8)
#define EPB 4096    // edges per partition block
#define NBLKP ((N_EDGES + EPB - 1) / EPB)  // 391 partition blocks
#define CAP 1536    // LDS-staged edges per 64-row quarter (avg 1023, +16 sigma)
#define CAPB 4800   // region capacity per bucket (avg 4092, +11 sigma)
#define OVFCAP 65536
#define GEMM_BLOCKS ((N_NODES + 255) / 256)  // 391
#define SPMM_GRID (8 * 4 * ((NBUCK + 7) / 8))  // 1568 (4 dead blocks)

// ---- workspace layout (bytes) ----------------------------------------------
// h_bf       [0,           25,600,000)   N_NODES*FT*2 (bf16)
// bucketed   [25,600,000,  40,614,400)   NBUCK regions x CAPB int2
// gcur       [40,614,400,  40,615,964)   NBUCK ints (bucket fill counts)
// novf       [40,615,964,  40,615,968)   1 int (overflow count)
// ovf_rec    [40,615,968,  41,140,256)   OVFCAP int2
// ovf_buck   [41,140,256,  41,402,400)   OVFCAP ints
#define OFF_H 0
#define OFF_BUCKETED 25600000
#define OFF_GCUR 40614400
#define OFF_NOVF 40615964
#define OFF_OVFREC 40615968
#define OFF_OVFBUCK 41140256
#define WS_NEEDED 41402400

typedef __attribute__((ext_vector_type(8))) short bf16x8;
typedef __attribute__((ext_vector_type(4))) float f32x4;

// bf16 helpers (RNE pack, shift-unpack).
static __device__ __forceinline__ ushort f2bf(float f) {
  const unsigned u = __float_as_uint(f);
  return (ushort)((u + 0x7FFF + ((u >> 16) & 1)) >> 16);
}
static __device__ __forceinline__ float bf2f(ushort s) {
  return __uint_as_float((unsigned)s << 16);
}

// ---------------------------------------------------------------------------
// FUSED gemm + partC2: grid = GEMM_BLOCKS + NBLKP.
// gemm half: MFMA projection h = x@W + b (bf16 out).
// partC2 half: LDS histogram (pass 1) -> bulk atomic reservation (one
// with-return atomicAdd per non-empty bucket: base in that bucket's fixed
// CAPB region) -> scatter (pass 2). No global scan. Overflow beyond CAPB
// spills to a global list (statistically never; spmm checks a counter).
// ---------------------------------------------------------------------------
__global__ __launch_bounds__(256) void fused_gemm_partC_kernel(
    const float* __restrict__ x,
    const float* __restrict__ W,
    const float* __restrict__ b,
    ushort* __restrict__ h,
    const int* __restrict__ erows,
    const int* __restrict__ ecols,
    const float* __restrict__ evals,
    int* gcur,
    int* novf,
    int2* __restrict__ ovf_rec,
    int* __restrict__ ovf_buck,
    int2* __restrict__ bucketed) {
  __shared__ __align__(16) ushort whi[16384];  // 32 KB (gemm half)
  __shared__ int cnt[NBUCK];                   // hist -> absolute cursor
  const int tid = threadIdx.x;

  if (blockIdx.x < GEMM_BLOCKS) {
    // ------------------------- gemm half ---------------------------------
    for (int idx = tid; idx < 16384; idx += 256) {
      const int k = idx >> 7;
      const int col = idx & 127;
      const ushort hi = f2bf(W[idx]);
      const int lane_ = (((k >> 3) & 3) << 4) | (col & 15);
      const int pos =
          ((((k >> 5) << 3) + (col >> 4)) * 64 + lane_) * 8 + (k & 7);
      whi[pos] = hi;
    }
    __syncthreads();

    const int w = tid >> 6;
    const int lane = tid & 63;
    const int r0 = blockIdx.x * 256 + w * 64;
    const int arow = lane & 15;
    const int kgrp = (lane >> 4) << 3;

    float bias_v[8];
#pragma unroll
    for (int ct = 0; ct < 8; ++ct) bias_v[ct] = b[ct * 16 + (lane & 15)];

    f32x4 acc[4][8];
#pragma unroll
    for (int rf = 0; rf < 4; ++rf)
#pragma unroll
      for (int ct = 0; ct < 8; ++ct) acc[rf][ct] = (f32x4){0.f, 0.f, 0.f, 0.f};

#pragma unroll
    for (int ks = 0; ks < 4; ++ks) {
      bf16x8 afr[4];
#pragma unroll
      for (int rf = 0; rf < 4; ++rf) {
        int r = r0 + rf * 16 + arow;
        r = (r < N_NODES) ? r : (N_NODES - 1);
        const float* xp = x + (size_t)r * FT + ks * 32 + kgrp;
        const float4 u0 = *(const float4*)xp;
        const float4 u1 = *(const float4*)(xp + 4);
        bf16x8 a;
        a[0] = (short)f2bf(u0.x);
        a[1] = (short)f2bf(u0.y);
        a[2] = (short)f2bf(u0.z);
        a[3] = (short)f2bf(u0.w);
        a[4] = (short)f2bf(u1.x);
        a[5] = (short)f2bf(u1.y);
        a[6] = (short)f2bf(u1.z);
        a[7] = (short)f2bf(u1.w);
        afr[rf] = a;
      }
#pragma unroll
      for (int ct = 0; ct < 8; ++ct) {
        const int fo = ((ks * 8 + ct) * 64 + lane) * 8;
        const bf16x8 bh = *(const bf16x8*)&whi[fo];
#pragma unroll
        for (int rf = 0; rf < 4; ++rf) {
          acc[rf][ct] = __builtin_amdgcn_mfma_f32_16x16x32_bf16(
              afr[rf], bh, acc[rf][ct], 0, 0, 0);
        }
      }
    }

    const int crow0 = (lane >> 4) << 2;
    const int ccol = lane & 15;
#pragma unroll
    for (int rf = 0; rf < 4; ++rf) {
#pragma unroll
      for (int ct = 0; ct < 8; ++ct) {
        const int col = ct * 16 + ccol;
#pragma unroll
        for (int i = 0; i < 4; ++i) {
          const int row = r0 + rf * 16 + crow0 + i;
          if (row < N_NODES)
            h[(size_t)row * FT + col] = f2bf(acc[rf][ct][i] + bias_v[ct]);
        }
      }
    }
  } else {
    // ------------------------- partC2 half -------------------------------
    const int bid = blockIdx.x - GEMM_BLOCKS;
    for (int j = tid; j < NBUCK; j += 256) cnt[j] = 0;
    __syncthreads();

    const int base4 = bid * (EPB / 4);
    // pass 1: histogram
#pragma unroll
    for (int it = 0; it < EPB / 4 / 256; ++it) {
      const int idx4 = base4 + it * 256 + tid;
      if (idx4 < N_EDGES / 4) {
        const int4 r = ((const int4*)erows)[idx4];
        atomicAdd(&cnt[r.x >> 8], 1);
        atomicAdd(&cnt[r.y >> 8], 1);
        atomicAdd(&cnt[r.z >> 8], 1);
        atomicAdd(&cnt[r.w >> 8], 1);
      }
    }
    __syncthreads();

    // bulk reservation: one with-return atomic per non-empty bucket
    for (int j = tid; j < NBUCK; j += 256) {
      const int hj = cnt[j];
      int base = 0;
      if (hj > 0) base = atomicAdd(&gcur[j], hj);
      // absolute cursor; cap enforced per-record at write time
      cnt[j] = j * CAPB + ((base < CAPB) ? base : CAPB);
    }
    __syncthreads();

    // pass 2: scatter
#pragma unroll
    for (int it = 0; it < EPB / 4 / 256; ++it) {
      const int idx4 = base4 + it * 256 + tid;
      if (idx4 < N_EDGES / 4) {
        const int4 r = ((const int4*)erows)[idx4];
        const int4 c = ((const int4*)ecols)[idx4];
        const float4 v = ((const float4*)evals)[idx4];
        int bb, p, lim;
        int2 rec;
#define SCAT(RR, CC, VV)                                           \
        bb = (RR) >> 8;                                            \
        rec.x = (((RR) & 255) << 24) | (CC);                       \
        rec.y = __float_as_int(VV);                                \
        p = atomicAdd(&cnt[bb], 1);                                \
        lim = bb * CAPB + CAPB;                                    \
        if (p < lim) {                                             \
          bucketed[p] = rec;                                       \
        } else {                                                   \
          const int op = atomicAdd(novf, 1);                       \
          if (op < OVFCAP) { ovf_rec[op] = rec; ovf_buck[op] = bb; } \
        }
        SCAT(r.x, c.x, v.x)
        SCAT(r.y, c.y, v.y)
        SCAT(r.z, c.z, v.z)
        SCAT(r.w, c.w, v.w)
#undef SCAT
      }
    }
  }
}

// ---------------------------------------------------------------------------
// Fused filter + sort + SpMM with XCD-aware swizzle: the 4 quarter-blocks of
// bucket b map to the SAME XCD and adjacent dispatch slots, so the bucket
// region re-read hits that XCD's L2.
// ---------------------------------------------------------------------------
__global__ __launch_bounds__(512) void spmm_bucket_kernel(
    const int2* __restrict__ bucketed,
    const int* __restrict__ gcur,
    const int* __restrict__ novf,
    const int2* __restrict__ ovf_rec,
    const int* __restrict__ ovf_buck,
    const ushort* __restrict__ h,
    float* __restrict__ out) {
  __shared__ int2 tmp[CAP];   // 12 KB unsorted stage
  __shared__ int2 eds[CAP];   // 12 KB sorted
  __shared__ int cnt[64];
  __shared__ int pos[64];
  __shared__ int cur[64];
  __shared__ int ns;
  const int p_ = blockIdx.x;
  const int x_ = p_ & 7;
  const int m_ = p_ >> 3;
  const int q = m_ & 3;
  const int b = 8 * (m_ >> 2) + x_;
  if (b >= NBUCK) return;
  const int t = threadIdx.x;
  const int beg = b * CAPB;
  const int fill = gcur[b];
  const int end = beg + ((fill < CAPB) ? fill : CAPB);
  const int nov = *novf;

  if (t < 64) cnt[t] = 0;
  if (t == 0) ns = 0;
  __syncthreads();

  for (int i = beg + t; i < end; i += 512) {
    const int2 rec = bucketed[i];
    const int r8 = ((unsigned)rec.x) >> 24;
    if ((r8 >> 6) == q) {
      const int p = atomicAdd(&ns, 1);
      if (p < CAP) {
        tmp[p] = rec;
        atomicAdd(&cnt[r8 & 63], 1);
      }
    }
  }
  __syncthreads();

  const int m = (ns < CAP) ? ns : CAP;
  const bool overflow = (ns > CAP);

  if (t < 64) pos[t] = cnt[t];
  __syncthreads();
#pragma unroll
  for (int d = 1; d < 64; d <<= 1) {
    int u = 0;
    if (t < 64 && t >= d) u = pos[t - d];
    __syncthreads();
    if (t < 64) pos[t] += u;
    __syncthreads();
  }
  if (t < 64) {
    const int excl = pos[t] - cnt[t];
    pos[t] = excl;
    cur[t] = excl;
  }
  __syncthreads();

  for (int i = t; i < m; i += 512) {
    const int2 rec = tmp[i];
    const int r6 = (((unsigned)rec.x) >> 24) & 63;
    const int p = atomicAdd(&cur[r6], 1);
    eds[p] = (int2){rec.x & 0x00FFFFFF, rec.y};
  }
  __syncthreads();

  const int g = t >> 5;
  const int lane = t & 31;
  const int j = lane * 4;

  for (int rr = 0; rr < 4; ++rr) {
    const int r = rr * 16 + g;
    const int row = b * 256 + q * 64 + r;
    const int rbeg = pos[r];
    const int rend = cur[r];

    float a0 = 0.f, a1 = 0.f, a2 = 0.f, a3 = 0.f;
    int e = rbeg;
    for (; e + 3 < rend; e += 4) {
      const int2 p0 = eds[e];
      const int2 p1 = eds[e + 1];
      const int2 p2 = eds[e + 2];
      const int2 p3 = eds[e + 3];
      const ushort4 q0 = *(const ushort4*)(h + (size_t)p0.x * FT + j);
      const ushort4 q1 = *(const ushort4*)(h + (size_t)p1.x * FT + j);
      const ushort4 q2 = *(const ushort4*)(h + (size_t)p2.x * FT + j);
      const ushort4 q3 = *(const ushort4*)(h + (size_t)p3.x * FT + j);
      const float v0 = __int_as_float(p0.y);
      const float v1 = __int_as_float(p1.y);
      const float v2 = __int_as_float(p2.y);
      const float v3 = __int_as_float(p3.y);
      a0 = fmaf(v0, bf2f(q0.x), a0);
      a1 = fmaf(v0, bf2f(q0.y), a1);
      a2 = fmaf(v0, bf2f(q0.z), a2);
      a3 = fmaf(v0, bf2f(q0.w), a3);
      a0 = fmaf(v1, bf2f(q1.x), a0);
      a1 = fmaf(v1, bf2f(q1.y), a1);
      a2 = fmaf(v1, bf2f(q1.z), a2);
      a3 = fmaf(v1, bf2f(q1.w), a3);
      a0 = fmaf(v2, bf2f(q2.x), a0);
      a1 = fmaf(v2, bf2f(q2.y), a1);
      a2 = fmaf(v2, bf2f(q2.z), a2);
      a3 = fmaf(v2, bf2f(q2.w), a3);
      a0 = fmaf(v3, bf2f(q3.x), a0);
      a1 = fmaf(v3, bf2f(q3.y), a1);
      a2 = fmaf(v3, bf2f(q3.z), a2);
      a3 = fmaf(v3, bf2f(q3.w), a3);
    }
    for (; e < rend; ++e) {
      const int2 p0 = eds[e];
      const float v0 = __int_as_float(p0.y);
      const ushort4 q0 = *(const ushort4*)(h + (size_t)p0.x * FT + j);
      a0 = fmaf(v0, bf2f(q0.x), a0);
      a1 = fmaf(v0, bf2f(q0.y), a1);
      a2 = fmaf(v0, bf2f(q0.z), a2);
      a3 = fmaf(v0, bf2f(q0.w), a3);
    }
    if (overflow) {  // LDS stage overflow: rescan this bucket's region
      int seen = 0;
      const int have = rend - rbeg;
      for (int i = beg; i < end; ++i) {
        const int2 rec = bucketed[i];
        const int r8 = ((unsigned)rec.x) >> 24;
        if ((r8 >> 6) == q && (r8 & 63) == r) {
          ++seen;
          if (seen > have) {
            const float v0 = __int_as_float(rec.y);
            const ushort4 q0 =
                *(const ushort4*)(h + (size_t)(rec.x & 0x00FFFFFF) * FT + j);
            a0 = fmaf(v0, bf2f(q0.x), a0);
            a1 = fmaf(v0, bf2f(q0.y), a1);
            a2 = fmaf(v0, bf2f(q0.z), a2);
            a3 = fmaf(v0, bf2f(q0.w), a3);
          }
        }
      }
    }
    if (nov > 0) {  // global region overflow: scan spill list (never taken)
      const int lim = (nov < OVFCAP) ? nov : OVFCAP;
      for (int i = 0; i < lim; ++i) {
        if (ovf_buck[i] == b) {
          const int2 rec = ovf_rec[i];
          const int r8 = ((unsigned)rec.x) >> 24;
          if ((r8 >> 6) == q && (r8 & 63) == r) {
            const float v0 = __int_as_float(rec.y);
            const ushort4 q0 =
                *(const ushort4*)(h + (size_t)(rec.x & 0x00FFFFFF) * FT + j);
            a0 = fmaf(v0, bf2f(q0.x), a0);
            a1 = fmaf(v0, bf2f(q0.y), a1);
            a2 = fmaf(v0, bf2f(q0.z), a2);
            a3 = fmaf(v0, bf2f(q0.w), a3);
          }
        }
      }
    }

    if (row < N_NODES) {
      float4 o;
      o.x = fmaxf(a0, 0.f);
      o.y = fmaxf(a1, 0.f);
      o.z = fmaxf(a2, 0.f);
      o.w = fmaxf(a3, 0.f);
      *(float4*)(out + (size_t)row * FT + j) = o;
    }
  }
}

// ---------------------------------------------------------------------------
// Fallback (small ws): standalone bf16-h gemm + atomic scatter + relu.
// ---------------------------------------------------------------------------
__global__ __launch_bounds__(256) void gemm_bias_kernel(
    const float* __restrict__ x,
    const float* __restrict__ W,
    const float* __restrict__ b,
    ushort* __restrict__ h) {
  __shared__ __align__(16) ushort whi[16384];
  const int tid = threadIdx.x;

  for (int idx = tid; idx < 16384; idx += 256) {
    const int k = idx >> 7;
    const int col = idx & 127;
    const ushort hi = f2bf(W[idx]);
    const int lane_ = (((k >> 3) & 3) << 4) | (col & 15);
    const int pos = ((((k >> 5) << 3) + (col >> 4)) * 64 + lane_) * 8 + (k & 7);
    whi[pos] = hi;
  }
  __syncthreads();

  const int w = tid >> 6;
  const int lane = tid & 63;
  const int r0 = blockIdx.x * 256 + w * 64;
  const int arow = lane & 15;
  const int kgrp = (lane >> 4) << 3;

  float bias_v[8];
#pragma unroll
  for (int ct = 0; ct < 8; ++ct) bias_v[ct] = b[ct * 16 + (lane & 15)];

  f32x4 acc[4][8];
#pragma unroll
  for (int rf = 0; rf < 4; ++rf)
#pragma unroll
    for (int ct = 0; ct < 8; ++ct) acc[rf][ct] = (f32x4){0.f, 0.f, 0.f, 0.f};

#pragma unroll
  for (int ks = 0; ks < 4; ++ks) {
    bf16x8 afr[4];
#pragma unroll
    for (int rf = 0; rf < 4; ++rf) {
      int r = r0 + rf * 16 + arow;
      r = (r < N_NODES) ? r : (N_NODES - 1);
      const float* xp = x + (size_t)r * FT + ks * 32 + kgrp;
      const float4 u0 = *(const float4*)xp;
      const float4 u1 = *(const float4*)(xp + 4);
      bf16x8 a;
      a[0] = (short)f2bf(u0.x);
      a[1] = (short)f2bf(u0.y);
      a[2] = (short)f2bf(u0.z);
      a[3] = (short)f2bf(u0.w);
      a[4] = (short)f2bf(u1.x);
      a[5] = (short)f2bf(u1.y);
      a[6] = (short)f2bf(u1.z);
      a[7] = (short)f2bf(u1.w);
      afr[rf] = a;
    }
#pragma unroll
    for (int ct = 0; ct < 8; ++ct) {
      const int fo = ((ks * 8 + ct) * 64 + lane) * 8;
      const bf16x8 bh = *(const bf16x8*)&whi[fo];
#pragma unroll
      for (int rf = 0; rf < 4; ++rf) {
        acc[rf][ct] = __builtin_amdgcn_mfma_f32_16x16x32_bf16(
            afr[rf], bh, acc[rf][ct], 0, 0, 0);
      }
    }
  }

  const int crow0 = (lane >> 4) << 2;
  const int ccol = lane & 15;
#pragma unroll
  for (int rf = 0; rf < 4; ++rf) {
#pragma unroll
    for (int ct = 0; ct < 8; ++ct) {
      const int col = ct * 16 + ccol;
#pragma unroll
      for (int i = 0; i < 4; ++i) {
        const int row = r0 + rf * 16 + crow0 + i;
        if (row < N_NODES)
          h[(size_t)row * FT + col] = f2bf(acc[rf][ct][i] + bias_v[ct]);
      }
    }
  }
}

__global__ __launch_bounds__(256) void edge_scatter_kernel(
    const int* __restrict__ erows,
    const int* __restrict__ ecols,
    const float* __restrict__ evals,
    const ushort* __restrict__ h,
    float* out) {
  const int tid = threadIdx.x;
  const int e = blockIdx.x * 8 + (tid >> 5);
  if (e >= N_EDGES) return;
  const int r = erows[e];
  const int c = ecols[e];
  const float v = evals[e];
  const int j = (tid & 31) * 4;
  const ushort4 q = *(const ushort4*)(h + (size_t)c * FT + j);
  float* op = out + (size_t)r * FT + j;
  atomicAdd(op + 0, v * bf2f(q.x));
  atomicAdd(op + 1, v * bf2f(q.y));
  atomicAdd(op + 2, v * bf2f(q.z));
  atomicAdd(op + 3, v * bf2f(q.w));
}

__global__ __launch_bounds__(256) void relu_kernel(float* out, int n4) {
  const int i = blockIdx.x * blockDim.x + threadIdx.x;
  if (i < n4) {
    float4 v = ((float4*)out)[i];
    v.x = fmaxf(v.x, 0.f);
    v.y = fmaxf(v.y, 0.f);
    v.z = fmaxf(v.z, 0.f);
    v.w = fmaxf(v.w, 0.f);
    ((float4*)out)[i] = v;
  }
}

extern "C" void kernel_launch(void* const* d_in, const int* in_sizes, int n_in,
                              void* d_out, int out_size, void* d_ws, size_t ws_size,
                              hipStream_t stream) {
  const float* x = (const float*)d_in[0];
  const int* erows = (const int*)d_in[1];
  const int* ecols = (const int*)d_in[2];
  const float* evals = (const float*)d_in[3];
  const float* W = (const float*)d_in[4];
  const float* b = (const float*)d_in[5];
  float* out = (float*)d_out;

  char* ws = (char*)d_ws;
  ushort* h = (ushort*)(ws + OFF_H);

  if (ws_size >= (size_t)WS_NEEDED) {
    int2* bucketed = (int2*)(ws + OFF_BUCKETED);
    int* gcur = (int*)(ws + OFF_GCUR);
    int* novf = (int*)(ws + OFF_NOVF);
    int2* ovf_rec = (int2*)(ws + OFF_OVFREC);
    int* ovf_buck = (int*)(ws + OFF_OVFBUCK);

    // zero gcur (NBUCK ints) + novf (1 int) — contiguous
    hipMemsetAsync(gcur, 0, (NBUCK + 1) * sizeof(int), stream);
    fused_gemm_partC_kernel<<<GEMM_BLOCKS + NBLKP, 256, 0, stream>>>(
        x, W, b, h, erows, ecols, evals, gcur, novf, ovf_rec, ovf_buck,
        bucketed);
    spmm_bucket_kernel<<<SPMM_GRID, 512, 0, stream>>>(
        bucketed, gcur, novf, ovf_rec, ovf_buck, h, out);
  } else {
    gemm_bias_kernel<<<GEMM_BLOCKS, 256, 0, stream>>>(x, W, b, h);
    hipMemsetAsync(d_out, 0, (size_t)out_size * sizeof(float), stream);
    edge_scatter_kernel<<<(N_EDGES + 7) / 8, 256, 0, stream>>>(erows, ecols,
                                                               evals, h, out);
    const int n4 = out_size / 4;
    relu_kernel<<<(n4 + 255) / 256, 256, 0, stream>>>(out, n4);
  }
}